// Round 1
// baseline (281.815 us; speedup 1.0000x reference)
//
#include <hip/hip_runtime.h>
#include <hip/hip_bf16.h>

// KAN layer as augmented GEMM:
//   Af[b, c*1024+i] = c==0 ? silu(x[b,i]) : basis_{c-1}(x[b,i])   (bf16)
//   Wf[o, c*1024+i] = c==0 ? base_w[o,i]  : spline_w[o,i,c-1]     (bf16)
//   out = Af @ Wf^T  (fp32 accum via MFMA)
#define B_DIM 8192
#define I_DIM 1024
#define O_DIM 1024
#define K_DIM 9216   // 9 * 1024

typedef __attribute__((ext_vector_type(8))) short short8;
typedef __attribute__((ext_vector_type(4))) float f32x4;

__device__ __forceinline__ unsigned short f2bf(float f) {
    unsigned u = __float_as_uint(f);
    unsigned r = 0x7fffu + ((u >> 16) & 1u);
    return (unsigned short)((u + r) >> 16);
}

__device__ __forceinline__ void llds16(const unsigned short* g, unsigned short* l) {
    __builtin_amdgcn_global_load_lds(
        (const __attribute__((address_space(1))) unsigned int*)g,
        (__attribute__((address_space(3))) unsigned int*)l,
        16, 0, 0);
}

// ---------------- expansion: weights ----------------
__global__ __launch_bounds__(256) void expand_w_kernel(
        const float* __restrict__ bw, const float* __restrict__ sw,
        unsigned short* __restrict__ Wf) {
    int idx = blockIdx.x * 256 + threadIdx.x;   // one thread: (o, 2 consecutive i)
    int o = idx >> 9;
    int i = (idx & 511) << 1;
    unsigned short* out = Wf + (size_t)o * K_DIM + i;
    const float* bp = bw + ((size_t)o << 10) + i;
    *(unsigned*)out = (unsigned)f2bf(bp[0]) | ((unsigned)f2bf(bp[1]) << 16);
    const float* sp = sw + (((size_t)o << 10) + i) * 8;   // 16 contiguous floats
    float v[16];
    #pragma unroll
    for (int n = 0; n < 16; ++n) v[n] = sp[n];
    #pragma unroll
    for (int n = 0; n < 8; ++n)
        *(unsigned*)(out + (size_t)(n + 1) * 1024) =
            (unsigned)f2bf(v[n]) | ((unsigned)f2bf(v[8 + n]) << 16);
}

// ---------------- expansion: activations ----------------
__global__ __launch_bounds__(256) void expand_a_kernel(
        const float* __restrict__ x, unsigned short* __restrict__ Af) {
    int idx = blockIdx.x * 256 + threadIdx.x;   // one thread: (b, 2 consecutive i)
    int b = idx >> 9;
    int i = (idx & 511) << 1;
    const float* xp = x + ((size_t)b << 10) + i;
    float x0 = xp[0], x1 = xp[1];
    unsigned short* out = Af + (size_t)b * K_DIM + i;
    // channel 0: silu
    float s0 = x0 / (1.0f + __expf(-x0));
    float s1 = x1 / (1.0f + __expf(-x1));
    *(unsigned*)out = (unsigned)f2bf(s0) | ((unsigned)f2bf(s1) << 16);
    // channels 1..8: quadratic B-spline basis (uniform knots -9..9 step 1.8)
    float t0 = (x0 + 9.0f) * (1.0f / 1.8f);
    float t1 = (x1 + 9.0f) * (1.0f / 1.8f);
    float fj0 = floorf(t0), fj1 = floorf(t1);
    int j0 = (int)fj0, j1 = (int)fj1;
    float u0 = t0 - fj0, u1 = t1 - fj1;
    float p0 = 0.5f * (1.f - u0) * (1.f - u0);
    float p1 = 0.5f * (-2.f * u0 * u0 + 2.f * u0 + 1.f);
    float p2 = 0.5f * u0 * u0;
    float q0 = 0.5f * (1.f - u1) * (1.f - u1);
    float q1 = 0.5f * (-2.f * u1 * u1 + 2.f * u1 + 1.f);
    float q2 = 0.5f * u1 * u1;
    #pragma unroll
    for (int n = 0; n < 8; ++n) {
        float v0 = (n == j0 - 2) ? p0 : (n == j0 - 1) ? p1 : (n == j0) ? p2 : 0.f;
        float v1 = (n == j1 - 2) ? q0 : (n == j1 - 1) ? q1 : (n == j1) ? q2 : 0.f;
        *(unsigned*)(out + (size_t)(n + 1) * 1024) =
            (unsigned)f2bf(v0) | ((unsigned)f2bf(v1) << 16);
    }
}

// ---------------- GEMM: out[M=8192, N=1024] = Af[M,K] * Wf[N,K]^T ----------------
#define BM 128
#define BN 128
#define BKK 32
#define NKB (K_DIM / BKK)   // 288

__global__ __launch_bounds__(256) void gemm_bt(
        const unsigned short* __restrict__ Af,
        const unsigned short* __restrict__ Wf,
        float* __restrict__ out) {
    __shared__ __align__(16) unsigned short As[2][BM * BKK];
    __shared__ __align__(16) unsigned short Bs[2][BN * BKK];

    const int tid = threadIdx.x;
    const int bn = blockIdx.x & 7;          // 8 N-blocks
    const int bm = blockIdx.x >> 3;         // 64 M-blocks
    const int mBase = bm * BM, nBase = bn * BN;

    const int lane = tid & 63;
    const int w = tid >> 6;                 // 4 waves, 2x2 grid of 64x64 sub-tiles
    const int wr = (w >> 1) * 64, wc = (w & 1) * 64;
    const int fr = lane & 15;               // fragment row/col
    const int ks = (lane >> 4) * 8;         // k-slot offset (0/8/16/24)

    f32x4 acc[4][4];
    #pragma unroll
    for (int m = 0; m < 4; ++m)
        #pragma unroll
        for (int n = 0; n < 4; ++n) acc[m][n] = (f32x4){0.f, 0.f, 0.f, 0.f};

    auto stage = [&](int kb, int buf) {
        #pragma unroll
        for (int it = 0; it < 2; ++it) {
            int lid = it * 256 + tid;              // 0..511
            int row = lid >> 2, c8 = (lid & 3) << 3;
            const unsigned short* ga = Af + (size_t)(mBase + row) * K_DIM + kb * BKK + c8;
            const unsigned short* gb = Wf + (size_t)(nBase + row) * K_DIM + kb * BKK + c8;
            // LDS dest: wave-uniform base; HW adds lane*16B -> linear row-major tile
            llds16(ga, &As[buf][(lid & ~63) * 8]);
            llds16(gb, &Bs[buf][(lid & ~63) * 8]);
        }
    };

    stage(0, 0);
    __syncthreads();   // drains vmcnt(0)

    for (int kb = 0; kb < NKB; ++kb) {
        const int cur = kb & 1;
        if (kb + 1 < NKB) stage(kb + 1, cur ^ 1);

        const unsigned short* A_ = As[cur];
        const unsigned short* B_ = Bs[cur];
        short8 a[4], b[4];
        #pragma unroll
        for (int m = 0; m < 4; ++m)
            a[m] = *(const short8*)&A_[(wr + m * 16 + fr) * BKK + ks];
        #pragma unroll
        for (int n = 0; n < 4; ++n)
            b[n] = *(const short8*)&B_[(wc + n * 16 + fr) * BKK + ks];
        #pragma unroll
        for (int m = 0; m < 4; ++m)
            #pragma unroll
            for (int n = 0; n < 4; ++n)
                acc[m][n] = __builtin_amdgcn_mfma_f32_16x16x32_bf16(a[m], b[n], acc[m][n], 0, 0, 0);

        __syncthreads();   // stage(kb+1) drained + everyone done reading cur
    }

    // epilogue: C/D layout col=lane&15, row=(lane>>4)*4+r
    const int orow = (lane >> 4) * 4;
    const int ocol = lane & 15;
    #pragma unroll
    for (int m = 0; m < 4; ++m)
        #pragma unroll
        for (int n = 0; n < 4; ++n) {
            size_t base = (size_t)(mBase + wr + m * 16 + orow) * O_DIM
                        + (nBase + wc + n * 16 + ocol);
            #pragma unroll
            for (int r = 0; r < 4; ++r)
                out[base + (size_t)r * O_DIM] = acc[m][n][r];
        }
}

extern "C" void kernel_launch(void* const* d_in, const int* in_sizes, int n_in,
                              void* d_out, int out_size, void* d_ws, size_t ws_size,
                              hipStream_t stream) {
    const float* x  = (const float*)d_in[0];
    const float* bw = (const float*)d_in[1];
    const float* sw = (const float*)d_in[2];
    float* out = (float*)d_out;

    // ws layout: Wf [1024 x 9216] bf16 (18.9 MB) then Af [8192 x 9216] bf16 (151 MB)
    unsigned short* Wf = (unsigned short*)d_ws;
    unsigned short* Af = Wf + (size_t)O_DIM * K_DIM;

    expand_w_kernel<<<(O_DIM * I_DIM / 2) / 256, 256, 0, stream>>>(bw, sw, Wf);
    expand_a_kernel<<<(B_DIM * I_DIM / 2) / 256, 256, 0, stream>>>(x, Af);
    gemm_bt<<<(B_DIM / BM) * (O_DIM / BN), 256, 0, stream>>>(Af, Wf, out);
}